// Round 2
// baseline (757.162 us; speedup 1.0000x reference)
//
#include <hip/hip_runtime.h>
#include <hip/hip_bf16.h>
#include <cstdint>
#include <cstddef>

// Problem constants (B, S, INP, HID) from the reference
#define B_   64
#define S_   2048
#define INP_ 512
#define HID_ 512

typedef float          floatx4  __attribute__((ext_vector_type(4)));
typedef __bf16         bf16x8   __attribute__((ext_vector_type(8)));
typedef unsigned short ushortx8 __attribute__((ext_vector_type(8)));

__device__ __forceinline__ unsigned short f2bf(float f) {
  unsigned u = __float_as_uint(f);
  u += 0x7FFFu + ((u >> 16) & 1u);          // round-to-nearest-even
  return (unsigned short)(u >> 16);
}
// tanh(x) = 1 - 2/(exp(2x)+1); exp(2x) = exp2(x * 2*log2(e)).  ~1e-6 accuracy, inf-safe.
__device__ __forceinline__ float fast_tanh(float x) {
  float u = __builtin_amdgcn_exp2f(x * 2.88539008177792681472f);
  return 1.0f - 2.0f * __builtin_amdgcn_rcpf(u + 1.0f);
}

// ---------------------------------------------------------------------------
// rowdot body: out[b,h] = bias[h] + dot(W[h,:], vec[b,:]), wave-per-16h.
// NPART=0: vec = vecs[b, 0..511]
// NPART!=0: vec[k] = sum_{c<nch} vecs[(c*B+b)*512 + k]   (partial-sum reduce)
// ---------------------------------------------------------------------------
__device__ __forceinline__ void rowdot_body(
    const float* __restrict__ W, const float* __restrict__ bias,
    const float* __restrict__ vecs, float* __restrict__ out,
    int nch, int npart, int xo, int b, int t, float* vs)
{
  const int w = t >> 6, lane = t & 63;
  for (int i = t; i < 512; i += 256) {
    float s;
    if (npart) {
      s = 0.0f;
      for (int c = 0; c < nch; ++c)
        s += vecs[((size_t)c * B_ + b) * INP_ + i];
    } else {
      s = vecs[(size_t)b * 512 + i];
    }
    vs[i] = s;
  }
  __syncthreads();
  float vl[8];
  #pragma unroll
  for (int j = 0; j < 8; ++j) vl[j] = vs[lane * 8 + j];
  const int h0 = xo * 64 + w * 16;
  #pragma unroll
  for (int i = 0; i < 16; ++i) {
    const int h = h0 + i;
    const float4* wr = (const float4*)(W + (size_t)h * 512 + lane * 8);
    float4 w0 = wr[0], w1 = wr[1];
    float d = w0.x*vl[0] + w0.y*vl[1] + w0.z*vl[2] + w0.w*vl[3]
            + w1.x*vl[4] + w1.y*vl[5] + w1.z*vl[6] + w1.w*vl[7];
    #pragma unroll
    for (int off = 32; off; off >>= 1) d += __shfl_xor(d, off);
    if (lane == 0) out[(size_t)b * 512 + h] = bias[h] + d;
  }
}

// ---------------------------------------------------------------------------
// prep: blocks [0,128): pack Wc -> bf16 MFMA A-fragment order.
//       blocks [128,640): hid[b,h] = inp[b,:]·Wl[h,:] + bl[h].
// pk[(m16*1024 + ks*64 + lane)*8 + j] = Wc[m16*16 + (lane&15)][ks*32 + (lane>>4)*8 + j]
// ---------------------------------------------------------------------------
__global__ __launch_bounds__(256) void prep_kernel(
    const float* __restrict__ inp, const float* __restrict__ Wl,
    const float* __restrict__ bl, float* __restrict__ hid,
    const float* __restrict__ Wc, unsigned short* __restrict__ pk)
{
  __shared__ float vs[512];
  const int t = threadIdx.x;
  if (blockIdx.x < 128) {
    int g = blockIdx.x * 256 + t;               // 32768 threads
    int l = g & 63, ks = (g >> 6) & 15, m16 = g >> 10;
    int row = m16 * 16 + (l & 15);
    int kb  = ks * 32 + (l >> 4) * 8;
    const float4* s = (const float4*)(Wc + (size_t)row * 512 + kb);
    float4 a = s[0], c = s[1];
    ushortx8 o = { f2bf(a.x), f2bf(a.y), f2bf(a.z), f2bf(a.w),
                   f2bf(c.x), f2bf(c.y), f2bf(c.z), f2bf(c.w) };
    *(ushortx8*)(pk + (size_t)g * 8) = o;
    return;
  }
  const int bx = blockIdx.x - 128;              // 0..511
  rowdot_body(Wl, bl, inp, hid, 0, 0, bx & 7, bx >> 3, t, vs);
}

// ---------------------------------------------------------------------------
// final hidden: hidden[b,h] = bc[h] + Wc[h,:]·cbar[b,:], cbar = sum of partials
// ---------------------------------------------------------------------------
__global__ __launch_bounds__(256) void hiddendot_kernel(
    const float* __restrict__ Wc, const float* __restrict__ bc,
    const float* __restrict__ partial, float* __restrict__ hidden, int nch)
{
  __shared__ float vs[512];
  rowdot_body(Wc, bc, partial, hidden, nch, 1, blockIdx.x, blockIdx.y, threadIdx.x, vs);
}

// ---------------------------------------------------------------------------
// att GEMM: per (b, s-tile of 64): ctx[h,s] = sum_k Wc[h,k]*context[b,s,k];
// att[b,s] = sum_h V[h]*tanh(hid[b,h] + ctx[h,s] + bc[h]).
// NO LDS staging: the per-phase context tile (64 s x 128 k fp32 = 32 KB) fits
// L1 and all 8 waves read the same tile — B-fragments load straight from
// global (2x float4 per lane), converted to bf16 in-register.  Raw s_barrier
// (no vmcnt drain) keeps waves phase-locked for L1 reuse.
// 8 waves x 64 h each -> acc = 64 regs/lane (was 128): no spill headroom.
// ---------------------------------------------------------------------------
__global__ __launch_bounds__(512, 2) void att_gemm_kernel(
    const float* __restrict__ context, const unsigned short* __restrict__ Wc_pk,
    const float* __restrict__ hid, const float* __restrict__ bc,
    const float* __restrict__ V, float* __restrict__ att)
{
  __shared__ float hid_sm[512];
  __shared__ float V_sm[512];
  __shared__ float bc_sm[512];
  __shared__ float att_sm[64];

  const int b    = blockIdx.y;
  const int s0   = blockIdx.x * 64;
  const int t    = threadIdx.x;
  const int lane = t & 63;
  const int w    = t >> 6;          // wave id: h-rows [w*64, w*64+64)
  const int quad = lane >> 4;
  const int l15  = lane & 15;

  for (int i = t; i < 512; i += 512) {
    hid_sm[i] = hid[b * 512 + i];
    V_sm[i]   = V[i];
    bc_sm[i]  = bc[i];
  }
  if (t < 64) att_sm[t] = 0.0f;

  floatx4 acc[4][4];
  #pragma unroll
  for (int m = 0; m < 4; ++m)
    #pragma unroll
    for (int n = 0; n < 4; ++n) { floatx4 z = {0.f,0.f,0.f,0.f}; acc[m][n] = z; }

  const unsigned short* apBase = Wc_pk + (size_t)(w * 4) * 8192 + (size_t)lane * 8;
  const float* bp = context + ((size_t)b * S_ + s0) * INP_;

  __syncthreads();                           // att_sm/params visible
  for (int phase = 0; phase < 4; ++phase) {
    if (phase) __builtin_amdgcn_s_barrier(); // rendezvous only: keep waves in
                                             // the same 32KB L1 window; loads
                                             // stay in flight across it.
    #pragma unroll
    for (int ksl = 0; ksl < 4; ++ksl) {
      const int ksg = phase * 4 + ksl;
      bf16x8 bfr[4];
      #pragma unroll
      for (int n = 0; n < 4; ++n) {
        const float* p = bp + (size_t)(n * 16 + l15) * INP_ + phase * 128 + (ksl * 4 + quad) * 8;
        floatx4 f0 = *(const floatx4*)p;
        floatx4 f1 = *(const floatx4*)(p + 4);
        bf16x8 r;
        r[0] = (__bf16)f0[0]; r[1] = (__bf16)f0[1];
        r[2] = (__bf16)f0[2]; r[3] = (__bf16)f0[3];
        r[4] = (__bf16)f1[0]; r[5] = (__bf16)f1[1];
        r[6] = (__bf16)f1[2]; r[7] = (__bf16)f1[3];
        bfr[n] = r;
      }
      #pragma unroll
      for (int m = 0; m < 4; ++m) {
        bf16x8 af = *(const bf16x8*)(apBase + (size_t)m * 8192 + (size_t)ksg * 512);
        #pragma unroll
        for (int n = 0; n < 4; ++n)
          acc[m][n] = __builtin_amdgcn_mfma_f32_16x16x32_bf16(af, bfr[n], acc[m][n], 0, 0, 0);
      }
    }
  }

  // Epilogue.  C/D layout (m89-verified): col(s) = lane&15, row(h) = quad*4 + reg.
  float attacc[4] = {0.f, 0.f, 0.f, 0.f};
  #pragma unroll
  for (int m = 0; m < 4; ++m) {
    const int hb = w * 64 + m * 16 + quad * 4;
    #pragma unroll
    for (int r = 0; r < 4; ++r) {
      const int h = hb + r;
      const float base = hid_sm[h] + bc_sm[h];
      const float vv = V_sm[h];
      #pragma unroll
      for (int n = 0; n < 4; ++n)
        attacc[n] += vv * fast_tanh(base + acc[m][n][r]);
    }
  }
  #pragma unroll
  for (int n = 0; n < 4; ++n) {
    float v = attacc[n];
    v += __shfl_xor(v, 16);
    v += __shfl_xor(v, 32);
    if (lane < 16) atomicAdd(&att_sm[n * 16 + l15], v);
  }
  __syncthreads();
  if (t < 64) att[b * S_ + s0 + t] = att_sm[t];
}

// ---------------------------------------------------------------------------
// cbar_sm: fused masked-softmax + weighted context reduction.
// Block (c,b): recomputes the row max/sum from att (L2-hot, 8KB), writes its
// alpha chunk, then partial[c][b][k] = sum_{s in chunk} alpha[b,s]*context[b,s,k].
// (hidden = Wc@cbar + bc by linearity, since sum_s alpha = 1.)
// ---------------------------------------------------------------------------
__global__ __launch_bounds__(256) void cbar_sm_kernel(
    const void* __restrict__ mask, const float* __restrict__ att,
    const float* __restrict__ context, float* __restrict__ alpha,
    float* __restrict__ partial, int rows)
{
  __shared__ int flags;
  __shared__ float red[8];
  __shared__ float a_sm[256];
  __shared__ float redbuf[1024];

  const int b = blockIdx.y, c = blockIdx.x, t = threadIdx.x;
  const int lane = t & 63, w = t >> 6;
  if (t == 0) flags = 0;
  __syncthreads();

  // mask-encoding autodetect (int32 / float32 / uint8), same logic as before
  int f = 0;
  const unsigned* mw = (const unsigned*)mask;
  for (int i = t; i < 512; i += 256) {
    unsigned v = mw[i];
    if (v > 1u) f |= 1;
    if (v != 0u && v != 0x3f800000u) f |= 2;
  }
  if (f) atomicOr(&flags, f);
  __syncthreads();
  const int fl = flags;
  const int mode = ((fl & 1) == 0) ? 0 : (((fl & 2) == 0) ? 1 : 2);

  // full-row masked max
  float v[8]; bool msk[8];
  float vmax = -1e30f;
  #pragma unroll
  for (int i = 0; i < 8; ++i) {
    int idx = i * 256 + t;
    bool m;
    if (mode == 0)      m = ((const int*)mask)[b * S_ + idx] != 0;
    else if (mode == 1) m = ((const float*)mask)[b * S_ + idx] != 0.0f;
    else                m = ((const unsigned char*)mask)[b * S_ + idx] != 0;
    msk[i] = m;
    v[i] = att[b * S_ + idx];
    if (!m) vmax = fmaxf(vmax, v[i]);
  }
  #pragma unroll
  for (int off = 32; off; off >>= 1) vmax = fmaxf(vmax, __shfl_xor(vmax, off));
  if (lane == 0) red[w] = vmax;
  __syncthreads();
  vmax = fmaxf(fmaxf(red[0], red[1]), fmaxf(red[2], red[3]));

  float e[8], s = 0.0f;
  #pragma unroll
  for (int i = 0; i < 8; ++i) {
    e[i] = msk[i] ? 0.0f : __builtin_amdgcn_exp2f((v[i] - vmax) * 1.4426950408889634f);
    s += e[i];
  }
  #pragma unroll
  for (int off = 32; off; off >>= 1) s += __shfl_xor(s, off);
  if (lane == 0) red[4 + w] = s;
  __syncthreads();
  s = red[4] + red[5] + red[6] + red[7];
  const float rinv = 1.0f / s;

  // write this block's alpha chunk + stage it in LDS
  const int sbase = c * rows;
  #pragma unroll
  for (int i = 0; i < 8; ++i) {
    int idx = i * 256 + t;
    int off = idx - sbase;
    if ((unsigned)off < (unsigned)rows) {
      float a = e[i] * rinv;
      alpha[(size_t)b * S_ + idx] = a;
      a_sm[off] = a;
    }
  }
  __syncthreads();

  // weighted reduction over this chunk: thread owns 4 cols, covers s=rp mod 2
  const int col = (t & 127) * 4, rp = t >> 7;
  const float* base2 = context + ((size_t)b * S_ + sbase) * INP_ + col;
  floatx4 a4 = {0.f, 0.f, 0.f, 0.f};
  #pragma unroll 8
  for (int sidx = rp; sidx < rows; sidx += 2) {
    floatx4 vv = *(const floatx4*)(base2 + (size_t)sidx * INP_);
    float a = a_sm[sidx];
    a4[0] = fmaf(a, vv[0], a4[0]);
    a4[1] = fmaf(a, vv[1], a4[1]);
    a4[2] = fmaf(a, vv[2], a4[2]);
    a4[3] = fmaf(a, vv[3], a4[3]);
  }
  *(floatx4*)&redbuf[rp * 512 + col] = a4;
  __syncthreads();
  if (t < 128) {
    floatx4 r0 = *(const floatx4*)&redbuf[t * 4];
    floatx4 r1 = *(const floatx4*)&redbuf[512 + t * 4];
    floatx4 o = r0 + r1;
    *(floatx4*)&partial[((size_t)c * B_ + b) * INP_ + t * 4] = o;
  }
}

// ---------------------------------------------------------------------------
extern "C" void kernel_launch(void* const* d_in, const int* in_sizes, int n_in,
                              void* d_out, int out_size, void* d_ws, size_t ws_size,
                              hipStream_t stream)
{
  const float* inp     = (const float*)d_in[0];
  const float* context = (const float*)d_in[1];
  const void*  mask    = d_in[2];
  const float* Wl      = (const float*)d_in[3];
  const float* bl      = (const float*)d_in[4];
  const float* Wc      = (const float*)d_in[5];
  const float* bc      = (const float*)d_in[6];
  const float* V       = (const float*)d_in[7];

  float* hidden = (float*)d_out;                 // [B, HID]
  float* alpha  = (float*)d_out + B_ * HID_;     // [B, S]

  char* ws = (char*)d_ws;
  const size_t HIDW_BYTES = (size_t)B_ * HID_ * 4;      // 128 KB
  const size_t ATT_BYTES  = (size_t)B_ * S_ * 4;        // 512 KB
  const size_t PK_BYTES   = (size_t)HID_ * INP_ * 2;    // 512 KB

  float* hid_ws      = (float*)ws;
  float* att_ws      = (float*)(ws + HIDW_BYTES);
  unsigned short* pk = (unsigned short*)(ws + HIDW_BYTES + ATT_BYTES);
  float* partial     = (float*)(ws + HIDW_BYTES + ATT_BYTES + PK_BYTES);

  const size_t rem = ws_size - (HIDW_BYTES + ATT_BYTES + PK_BYTES);
  int nch = 32;                                   // s-chunks for cbar partials
  while (nch > 8 && (size_t)nch * B_ * INP_ * 4 > rem) nch >>= 1;
  const int rows = S_ / nch;

  prep_kernel<<<640, 256, 0, stream>>>(inp, Wl, bl, hid_ws, Wc, pk);
  att_gemm_kernel<<<dim3(S_ / 64, B_), 512, 0, stream>>>(context, pk, hid_ws, bc, V, att_ws);
  cbar_sm_kernel<<<dim3(nch, B_), 256, 0, stream>>>(mask, att_ws, context, alpha, partial, rows);
  hiddendot_kernel<<<dim3(HID_ / 64, B_), 256, 0, stream>>>(Wc, bc, partial, hidden, nch);
}

// Round 3
// 490.776 us; speedup vs baseline: 1.5428x; 1.5428x over previous
//
#include <hip/hip_runtime.h>
#include <hip/hip_bf16.h>
#include <cstdint>
#include <cstddef>

// Problem constants (B, S, INP, HID) from the reference
#define B_   64
#define S_   2048
#define INP_ 512
#define HID_ 512
#define NCH_ 32          // s-tiles per row (= att_gemm grid.x)

typedef float          floatx4  __attribute__((ext_vector_type(4)));
typedef __bf16         bf16x8   __attribute__((ext_vector_type(8)));
typedef unsigned short ushortx8 __attribute__((ext_vector_type(8)));
typedef unsigned short ushortx4 __attribute__((ext_vector_type(4)));

#define K2E 1.4426950408889634f

__device__ __forceinline__ unsigned short f2bf(float f) {
  unsigned u = __float_as_uint(f);
  u += 0x7FFFu + ((u >> 16) & 1u);          // round-to-nearest-even
  return (unsigned short)(u >> 16);
}
__device__ __forceinline__ float bf2f(unsigned short h) {
  return __uint_as_float(((unsigned)h) << 16);
}
// tanh(x) = 1 - 2/(exp(2x)+1); exp(2x) = exp2(x * 2*log2(e)).  ~1e-6 accuracy, inf-safe.
__device__ __forceinline__ float fast_tanh(float x) {
  float u = __builtin_amdgcn_exp2f(x * 2.88539008177792681472f);
  return 1.0f - 2.0f * __builtin_amdgcn_rcpf(u + 1.0f);
}

// mask-encoding autodetect shared logic: returns 0=int32, 1=float32, 2=uint8
__device__ __forceinline__ int detect_mask_mode(const void* mask, int t, int* flags) {
  if (t == 0) *flags = 0;
  __syncthreads();
  int f = 0;
  const unsigned* mw = (const unsigned*)mask;
  for (int i = t; i < 512; i += 256) {
    unsigned v = mw[i];
    if (v > 1u) f |= 1;
    if (v != 0u && v != 0x3f800000u) f |= 2;
  }
  if (f) atomicOr(flags, f);
  __syncthreads();
  const int fl = *flags;
  return ((fl & 1) == 0) ? 0 : (((fl & 2) == 0) ? 1 : 2);
}
__device__ __forceinline__ bool mask_at(const void* mask, int mode, size_t idx) {
  if (mode == 0) return ((const int*)mask)[idx] != 0;
  if (mode == 1) return ((const float*)mask)[idx] != 0.0f;
  return ((const unsigned char*)mask)[idx] != 0;
}

// ---------------------------------------------------------------------------
// prep: blocks [0,128): pack Wc -> bf16 MFMA A-fragment order.
//       blocks [128,640): hid[b,h] = inp[b,:]·Wl[h,:] + bl[h].
// pk[(m16*1024 + ks*64 + lane)*8 + j] = Wc[m16*16 + (lane&15)][ks*32 + (lane>>4)*8 + j]
// ---------------------------------------------------------------------------
__global__ __launch_bounds__(256) void prep_kernel(
    const float* __restrict__ inp, const float* __restrict__ Wl,
    const float* __restrict__ bl, float* __restrict__ hid,
    const float* __restrict__ Wc, unsigned short* __restrict__ pk)
{
  __shared__ float vs[512];
  const int t = threadIdx.x;
  if (blockIdx.x < 128) {
    int g = blockIdx.x * 256 + t;               // 32768 threads
    int l = g & 63, ks = (g >> 6) & 15, m16 = g >> 10;
    int row = m16 * 16 + (l & 15);
    int kb  = ks * 32 + (l >> 4) * 8;
    const float4* s = (const float4*)(Wc + (size_t)row * 512 + kb);
    float4 a = s[0], c = s[1];
    ushortx8 o = { f2bf(a.x), f2bf(a.y), f2bf(a.z), f2bf(a.w),
                   f2bf(c.x), f2bf(c.y), f2bf(c.z), f2bf(c.w) };
    *(ushortx8*)(pk + (size_t)g * 8) = o;
    return;
  }
  const int bx = blockIdx.x - 128;              // 0..511
  const int xo = bx & 7, b = bx >> 3;
  const int w = t >> 6, lane = t & 63;
  for (int i = t; i < 512; i += 256) vs[i] = inp[(size_t)b * 512 + i];
  __syncthreads();
  float vl[8];
  #pragma unroll
  for (int j = 0; j < 8; ++j) vl[j] = vs[lane * 8 + j];
  const int h0 = xo * 64 + w * 16;
  #pragma unroll
  for (int i = 0; i < 16; ++i) {
    const int h = h0 + i;
    const float4* wr = (const float4*)(Wl + (size_t)h * 512 + lane * 8);
    float4 w0 = wr[0], w1 = wr[1];
    float d = w0.x*vl[0] + w0.y*vl[1] + w0.z*vl[2] + w0.w*vl[3]
            + w1.x*vl[4] + w1.y*vl[5] + w1.z*vl[6] + w1.w*vl[7];
    #pragma unroll
    for (int off = 32; off; off >>= 1) d += __shfl_xor(d, off);
    if (lane == 0) hid[(size_t)b * 512 + h] = bl[h] + d;
  }
}

// ---------------------------------------------------------------------------
// att GEMM + tile-softmax partials (flash-style, round-0 proven MFMA core).
// Per (s-tile c, b): ctx[h,s] = sum_k Wc[h,k]*context[b,s,k] (bf16 MFMA);
// att[b,s] = sum_h V[h]*tanh(hid+ctx+bc).  Then, with the full 64x512 context
// tile PERSISTENT in LDS (bf16, 64KB), tile-local softmax partials:
//   m_c = max unmasked att;  w_s = e^(att_s-m_c);  l_c = sum w_s;
//   partial_c[k] = sum_s w_s * context[b,s,k].
// Eliminates the second 256MB context pass entirely.
// ---------------------------------------------------------------------------
__global__ __launch_bounds__(256, 2) void att_gemm_kernel(
    const float* __restrict__ context, const unsigned short* __restrict__ Wc_pk,
    const float* __restrict__ hid, const float* __restrict__ bc,
    const float* __restrict__ V, const void* __restrict__ mask,
    float* __restrict__ att, float* __restrict__ partial,
    float* __restrict__ mt, float* __restrict__ lt)
{
  // full context tile: 64 s-rows x 512 k (bf16), per-128-chunk XOR swizzle
  __shared__ alignas(16) unsigned short bsm[64 * 512];   // 64 KB
  __shared__ float hid_sm[512];
  __shared__ float V_sm[512];
  __shared__ float bc_sm[512];
  __shared__ float att_sm[64];
  __shared__ float w_sm[64];
  __shared__ int   flags;

  const int b    = blockIdx.y;
  const int c    = blockIdx.x;
  const int s0   = c * 64;
  const int t    = threadIdx.x;
  const int lane = t & 63;
  const int w    = t >> 6;          // wave id: h-rows [w*128, w*128+128)
  const int quad = lane >> 4;
  const int l15  = lane & 15;

  const int mode = detect_mask_mode(mask, t, &flags);   // has 2 syncthreads

  for (int i = t; i < 512; i += 256) {
    hid_sm[i] = hid[b * 512 + i];
    V_sm[i]   = V[i];
    bc_sm[i]  = bc[i];
  }
  if (t < 64) att_sm[t] = 0.0f;

  floatx4 acc[8][4];
  #pragma unroll
  for (int m = 0; m < 8; ++m)
    #pragma unroll
    for (int n = 0; n < 4; ++n) { floatx4 z = {0.f,0.f,0.f,0.f}; acc[m][n] = z; }

  const unsigned short* apBase = Wc_pk + (size_t)(w * 8) * 8192 + lane * 8;
  const float* src = context + ((size_t)b * S_ + s0) * INP_;

  for (int phase = 0; phase < 4; ++phase) {
    __syncthreads();
    // stage context[b, s0..s0+64)[phase*128 .. +128) -> bf16 LDS, swizzled
    #pragma unroll
    for (int i = 0; i < 8; ++i) {
      int id  = t + i * 256;                  // 0..2047, 32 float4-chunks per row
      int row = id >> 5;
      int c4  = id & 31;
      float4 f = *(const float4*)(src + (size_t)row * INP_ + phase * 128 + c4 * 4);
      int chunk = c4 >> 1, half = c4 & 1;
      int sw = chunk ^ (row & 7);
      ushortx4 hv = { f2bf(f.x), f2bf(f.y), f2bf(f.z), f2bf(f.w) };
      *(ushortx4*)(&bsm[row * 512 + phase * 128 + sw * 8 + half * 4]) = hv;
    }
    __syncthreads();
    #pragma unroll
    for (int ksl = 0; ksl < 4; ++ksl) {
      const int ksg = phase * 4 + ksl;
      bf16x8 af[8];
      #pragma unroll
      for (int m = 0; m < 8; ++m)
        af[m] = *(const bf16x8*)(apBase + (size_t)m * 8192 + ksg * 512);
      bf16x8 bfr[4];
      #pragma unroll
      for (int n = 0; n < 4; ++n) {
        int row = n * 16 + l15;
        int cc  = ksl * 4 + quad;
        bfr[n] = *(const bf16x8*)(&bsm[row * 512 + phase * 128 + ((cc ^ (row & 7)) * 8)]);
      }
      #pragma unroll
      for (int m = 0; m < 8; ++m)
        #pragma unroll
        for (int n = 0; n < 4; ++n)
          acc[m][n] = __builtin_amdgcn_mfma_f32_16x16x32_bf16(af[m], bfr[n], acc[m][n], 0, 0, 0);
    }
  }

  // ---- att epilogue.  C/D layout (m89-verified): col(s)=lane&15, row(h)=quad*4+reg.
  float attacc[4] = {0.f, 0.f, 0.f, 0.f};
  #pragma unroll
  for (int m = 0; m < 8; ++m) {
    const int hb = w * 128 + m * 16 + quad * 4;
    #pragma unroll
    for (int r = 0; r < 4; ++r) {
      const int h = hb + r;
      const float base = hid_sm[h] + bc_sm[h];
      const float vv = V_sm[h];
      #pragma unroll
      for (int n = 0; n < 4; ++n)
        attacc[n] += vv * fast_tanh(base + acc[m][n][r]);
    }
  }
  #pragma unroll
  for (int n = 0; n < 4; ++n) {
    float v = attacc[n];
    v += __shfl_xor(v, 16);
    v += __shfl_xor(v, 32);
    if (lane < 16) atomicAdd(&att_sm[n * 16 + l15], v);
  }
  __syncthreads();

  // ---- tile softmax: m_c, w_s, l_c (threads 0..63 = wave 0)
  if (t < 64) {
    att[(size_t)b * S_ + s0 + t] = att_sm[t];
    const bool m = mask_at(mask, mode, (size_t)b * S_ + s0 + t);
    const float av = att_sm[t];
    float mv = m ? -1e30f : av;
    #pragma unroll
    for (int off = 32; off; off >>= 1) mv = fmaxf(mv, __shfl_xor(mv, off));
    const float wv = m ? 0.0f : __builtin_amdgcn_exp2f((av - mv) * K2E);
    w_sm[t] = wv;
    float lv = wv;
    #pragma unroll
    for (int off = 32; off; off >>= 1) lv += __shfl_xor(lv, off);
    if (t == 0) { mt[b * NCH_ + c] = mv; lt[b * NCH_ + c] = lv; }
  }
  __syncthreads();

  // ---- weighted tile reduction: partial_c[k] = sum_s w_s * ctx_tile[s,k]
  // thread owns k = {2t, 2t+1}; LDS index = unswizzled ^ ((s&7)<<3).
  {
    const int k0 = t * 2;
    const int p  = k0 >> 7, kl = k0 & 127;
    const int c4 = kl >> 2, j = kl & 3;
    const int idxu = p * 128 + (c4 >> 1) * 8 + (c4 & 1) * 4 + j;
    float ax = 0.f, ay = 0.f;
    #pragma unroll 8
    for (int s = 0; s < 64; ++s) {
      const unsigned v = *(const unsigned*)(&bsm[s * 512 + (idxu ^ ((s & 7) << 3))]);
      const float wv = w_sm[s];
      ax = fmaf(wv, bf2f((unsigned short)(v & 0xffffu)), ax);
      ay = fmaf(wv, bf2f((unsigned short)(v >> 16)), ay);
    }
    float2 o; o.x = ax; o.y = ay;
    *(float2*)(partial + ((size_t)c * B_ + b) * INP_ + k0) = o;
  }
}

// ---------------------------------------------------------------------------
// finalize: per b, combine tile (m_c, l_c) -> global (M, L); write alpha and
// the per-tile rescale sc[c] = e^(m_c - M) / L.
// ---------------------------------------------------------------------------
__global__ __launch_bounds__(256) void finalize_kernel(
    const void* __restrict__ mask, const float* __restrict__ att,
    const float* __restrict__ mt, const float* __restrict__ lt,
    float* __restrict__ sc, float* __restrict__ alpha)
{
  __shared__ int flags;
  __shared__ float Msh, Lsh;
  const int b = blockIdx.x, t = threadIdx.x;
  const int mode = detect_mask_mode(mask, t, &flags);

  if (t < 32) {
    float m = mt[b * NCH_ + t];
    #pragma unroll
    for (int off = 16; off; off >>= 1) m = fmaxf(m, __shfl_xor(m, off));
    float e = __builtin_amdgcn_exp2f((mt[b * NCH_ + t] - m) * K2E) * lt[b * NCH_ + t];
    #pragma unroll
    for (int off = 16; off; off >>= 1) e += __shfl_xor(e, off);
    if (t == 0) { Msh = m; Lsh = e; }
  }
  __syncthreads();
  const float M = Msh;
  const float rL = 1.0f / Lsh;
  if (t < 32) sc[b * NCH_ + t] = __builtin_amdgcn_exp2f((mt[b * NCH_ + t] - M) * K2E) * rL;

  #pragma unroll
  for (int i = 0; i < 8; ++i) {
    const int idx = i * 256 + t;
    const bool m = mask_at(mask, mode, (size_t)b * S_ + idx);
    const float a = m ? 0.0f
                      : __builtin_amdgcn_exp2f((att[(size_t)b * S_ + idx] - M) * K2E) * rL;
    alpha[(size_t)b * S_ + idx] = a;
  }
}

// ---------------------------------------------------------------------------
// hidden[b,h] = bc[h] + Wc[h,:] · cbar[b,:],  cbar = sum_c sc[c]*partial[c][b]
// ---------------------------------------------------------------------------
__global__ __launch_bounds__(256) void hiddendot_kernel(
    const float* __restrict__ Wc, const float* __restrict__ bc,
    const float* __restrict__ partial, const float* __restrict__ sc,
    float* __restrict__ hidden)
{
  __shared__ float vs[512];
  __shared__ float scs[NCH_];
  const int b = blockIdx.y, t = threadIdx.x;
  const int w = t >> 6, lane = t & 63;
  if (t < NCH_) scs[t] = sc[b * NCH_ + t];
  __syncthreads();
  for (int i = t; i < 512; i += 256) {
    float s = 0.0f;
    #pragma unroll 4
    for (int c = 0; c < NCH_; ++c)
      s += scs[c] * partial[((size_t)c * B_ + b) * INP_ + i];
    vs[i] = s;
  }
  __syncthreads();
  float vl[8];
  #pragma unroll
  for (int j = 0; j < 8; ++j) vl[j] = vs[lane * 8 + j];
  const int h0 = blockIdx.x * 64 + w * 16;
  #pragma unroll
  for (int i = 0; i < 16; ++i) {
    const int h = h0 + i;
    const float4* wr = (const float4*)(Wc + (size_t)h * 512 + lane * 8);
    float4 w0 = wr[0], w1 = wr[1];
    float d = w0.x*vl[0] + w0.y*vl[1] + w0.z*vl[2] + w0.w*vl[3]
            + w1.x*vl[4] + w1.y*vl[5] + w1.z*vl[6] + w1.w*vl[7];
    #pragma unroll
    for (int off = 32; off; off >>= 1) d += __shfl_xor(d, off);
    if (lane == 0) hidden[(size_t)b * 512 + h] = bc[h] + d;
  }
}

// ---------------------------------------------------------------------------
extern "C" void kernel_launch(void* const* d_in, const int* in_sizes, int n_in,
                              void* d_out, int out_size, void* d_ws, size_t ws_size,
                              hipStream_t stream)
{
  const float* inp     = (const float*)d_in[0];
  const float* context = (const float*)d_in[1];
  const void*  mask    = d_in[2];
  const float* Wl      = (const float*)d_in[3];
  const float* bl      = (const float*)d_in[4];
  const float* Wc      = (const float*)d_in[5];
  const float* bc      = (const float*)d_in[6];
  const float* V       = (const float*)d_in[7];

  float* hidden = (float*)d_out;                 // [B, HID]
  float* alpha  = (float*)d_out + B_ * HID_;     // [B, S]

  char* ws = (char*)d_ws;
  const size_t HIDW = (size_t)B_ * HID_ * 4;           // 128 KB
  const size_t ATT  = (size_t)B_ * S_ * 4;             // 512 KB
  const size_t PK   = (size_t)HID_ * INP_ * 2;         // 512 KB
  const size_t PART = (size_t)NCH_ * B_ * INP_ * 4;    // 4 MB
  const size_t MT   = (size_t)B_ * NCH_ * 4;           // 8 KB

  float* hid_ws      = (float*)ws;
  float* att_ws      = (float*)(ws + HIDW);
  unsigned short* pk = (unsigned short*)(ws + HIDW + ATT);
  float* partial     = (float*)(ws + HIDW + ATT + PK);
  float* mt          = (float*)(ws + HIDW + ATT + PK + PART);
  float* lt          = (float*)(ws + HIDW + ATT + PK + PART + MT);
  float* sc          = (float*)(ws + HIDW + ATT + PK + PART + 2 * MT);

  prep_kernel<<<640, 256, 0, stream>>>(inp, Wl, bl, hid_ws, Wc, pk);
  att_gemm_kernel<<<dim3(NCH_, B_), 256, 0, stream>>>(
      context, pk, hid_ws, bc, V, mask, att_ws, partial, mt, lt);
  finalize_kernel<<<B_, 256, 0, stream>>>(mask, att_ws, mt, lt, sc, alpha);
  hiddendot_kernel<<<dim3(HID_ / 64, B_), 256, 0, stream>>>(Wc, bc, partial, sc, hidden);
}